// Round 7
// baseline (957.990 us; speedup 1.0000x reference)
//
#include <hip/hip_runtime.h>
#include <math.h>

#define Bv 8
#define Pv 12
#define Nv 5000
#define Hv 8
#define Ev 50000
#define NBv 8
#define TD1v 64
#define NIMG (Bv * Pv)          // 96 images
#define BLKS_PER_IMG 20         // ceil(5000/256)
#define ECAP 4096               // LDS edge-stage capacity per block (32 KB)

// correctly-rounded f32 of 10^(d/4), d=0..15 (matches numpy float32 powf)
__device__ __constant__ float POW10Q[16] = {
  1.0f, 1.7782794100389228f, 3.1622776601683795f, 5.623413251903491f,
  10.0f, 17.78279410038923f, 31.622776601683793f, 56.23413251903491f,
  100.0f, 177.82794100389228f, 316.22776601683796f, 562.341325190349f,
  1000.0f, 1778.2794100389228f, 3162.2776601683795f, 5623.413251903491f
};

// ---------------- setup: time-embedding chain, per-block t vectors, softmax(attn)
__global__ void k_setup(const int* timei, const float* attn,
                        const float* te_w1, const float* te_b1,
                        const float* te_w2, const float* te_b2,
                        const float* bt_w1, const float* bt_b1,
                        const float* bt_w2, const float* bt_b2,
                        float* t_all, float* a9) {
  __shared__ float te0[Bv][32];
  __shared__ float te1[Bv][64];
  __shared__ float te2[Bv][64];
  int t = threadIdx.x; // 64 threads
  for (int idx = t; idx < Bv * 16; idx += 64) {
    int b = idx >> 4, d = idx & 15;
    float e = (float)timei[b] * POW10Q[d];        // f32 rounding as in numpy
    te0[b][d]      = (float)sin((double)e);        // accurate sin at the f32 arg
    te0[b][d + 16] = (float)cos((double)e);
  }
  __syncthreads();
  for (int idx = t; idx < Bv * 64; idx += 64) {
    int b = idx >> 6, j = idx & 63;
    float s = te_b1[j];
    for (int k = 0; k < 32; ++k) s += te0[b][k] * te_w1[k * 64 + j];
    te1[b][j] = s / (1.0f + expf(-s));             // silu
  }
  __syncthreads();
  for (int idx = t; idx < Bv * 64; idx += 64) {
    int b = idx >> 6, j = idx & 63;
    float s = te_b2[j];
    for (int k = 0; k < 64; ++k) s += te1[b][k] * te_w2[k * 64 + j];
    te2[b][j] = s / (1.0f + expf(-s));
  }
  __syncthreads();
  {
    int i = t >> 3, b = t & 7;  // 64 (block,batch) pairs
    float u[Hv];
    for (int j = 0; j < Hv; ++j) {
      float s = bt_b1[i * Hv + j];
      for (int k = 0; k < TD1v; ++k) s += te2[b][k] * bt_w1[(i * TD1v + k) * Hv + j];
      u[j] = fmaxf(s, 0.0f);
    }
    for (int ch = 0; ch < Hv; ++ch) {
      float s = bt_b2[i * Hv + ch];
      for (int j = 0; j < Hv; ++j) s += u[j] * bt_w2[(i * Hv + j) * Hv + ch];
      t_all[(i * Bv + b) * Hv + ch] = s;
    }
  }
  if (t == 0) {
    float m = attn[0];
    for (int i = 1; i < 9; ++i) m = fmaxf(m, attn[i]);
    float s = 0.f, ex[9];
    for (int i = 0; i < 9; ++i) { ex[i] = expf(attn[i] - m); s += ex[i]; }
    for (int i = 0; i < 9; ++i) a9[i] = ex[i] / s;
  }
}

// ---------------- positional projection, once: posp[n][ch]
__global__ void k_posp(const float* pos, const float* pw1, const float* pb1,
                       const float* pw2, const float* pb2, float* posp) {
  int n = blockIdx.x * blockDim.x + threadIdx.x;
  if (n >= Nv) return;
  const float4* pr = (const float4*)(pos + (size_t)n * Hv);
  float4 r0 = pr[0], r1 = pr[1];
  float x[8] = {r0.x, r0.y, r0.z, r0.w, r1.x, r1.y, r1.z, r1.w};
  float u[8];
  #pragma unroll
  for (int j = 0; j < 8; ++j) {
    float s = pb1[j];
    #pragma unroll
    for (int k = 0; k < 8; ++k) s += x[k] * pw1[k * 8 + j];
    u[j] = fmaxf(s, 0.f);
  }
  float o[8];
  #pragma unroll
  for (int ch = 0; ch < 8; ++ch) {
    float s = pb2[ch];
    #pragma unroll
    for (int j = 0; j < 8; ++j) s += u[j] * pw2[j * 8 + ch];
    o[ch] = s;
  }
  float4* po = (float4*)(posp + (size_t)n * Hv);
  po[0] = make_float4(o[0], o[1], o[2], o[3]);
  po[1] = make_float4(o[4], o[5], o[6], o[7]);
}

// zero deg/cursor + all stats slots
__global__ void k_zero(float* deg, int* cursor, float* stats) {
  int i = blockIdx.x * blockDim.x + threadIdx.x;
  if (i < Nv) { deg[i] = 0.f; cursor[i] = 0; }
  if (i < NBv * 2 * NIMG * 2) stats[i] = 0.f;
}

__global__ void k_deg(const int* eidx, float* deg) {
  int e = blockIdx.x * blockDim.x + threadIdx.x;
  if (e < Ev) atomicAdd(&deg[eidx[Ev + e]], 1.0f);
}

__global__ void k_dinv(const float* deg, float* dinv) {
  int n = blockIdx.x * blockDim.x + threadIdx.x;
  if (n < Nv) {
    float d = deg[n];
    dinv[n] = d > 0.f ? (float)(1.0 / sqrt((double)d)) : 0.f;
  }
}

// single-block Hillis-Steele scan of per-dst counts -> row_ptr[0..Nv]
__global__ void k_scan(const float* deg, int* row_ptr) {
  __shared__ int buf[1024];
  __shared__ int base_s;
  int t = threadIdx.x;
  if (t == 0) { base_s = 0; row_ptr[0] = 0; }
  __syncthreads();
  for (int c = 0; c < 5; ++c) {
    int i = c * 1024 + t;
    int v = (i < Nv) ? (int)(deg[i] + 0.5f) : 0;
    buf[t] = v;
    __syncthreads();
    for (int off = 1; off < 1024; off <<= 1) {
      int add = (t >= off) ? buf[t - off] : 0;
      __syncthreads();
      buf[t] += add;
      __syncthreads();
    }
    int base = base_s;
    if (i < Nv) row_ptr[i + 1] = base + buf[t];
    __syncthreads();
    if (t == 1023) base_s = base + buf[1023];
    __syncthreads();
  }
}

// CSR fill: packed (src_bits, w) per edge
__global__ void k_csr(const int* eidx, const float* dinv, const int* row_ptr,
                      int* cursor, float2* epack) {
  int e = blockIdx.x * blockDim.x + threadIdx.x;
  if (e >= Ev) return;
  int s = eidx[e], d = eidx[Ev + e];
  int slot = atomicAdd(&cursor[d], 1);
  int pos = row_ptr[d] + slot;
  epack[pos] = make_float2(__int_as_float(s), dinv[s] * dinv[d]);
}

// ---------------- per block-iter, image-independent: Gw[i][n]=Σ w_e gnw_i[src], Gb likewise
__global__ __launch_bounds__(256) void k_gwb(
    const int* __restrict__ row_ptr, const float2* __restrict__ epack,
    const float* __restrict__ gn_w, const float* __restrict__ gn_b,
    float* __restrict__ Gw, float* __restrict__ Gb) {
  int id = blockIdx.x * 256 + threadIdx.x;
  if (id >= NBv * Nv) return;
  int i = id / Nv, n = id % Nv;
  const float* gw = gn_w + (size_t)i * Nv * Hv;
  const float* gb = gn_b + (size_t)i * Nv * Hv;
  float aw[8] = {0,0,0,0,0,0,0,0}, ab[8] = {0,0,0,0,0,0,0,0};
  int e0 = row_ptr[n], e1 = row_ptr[n + 1];
  for (int e = e0; e < e1; ++e) {
    float2 ep = epack[e];
    int s = __float_as_int(ep.x);
    float w = ep.y;
    const float4* wr = (const float4*)(gw + (size_t)s * Hv);
    const float4* br = (const float4*)(gb + (size_t)s * Hv);
    float4 w0 = wr[0], w1 = wr[1], b0 = br[0], b1 = br[1];
    aw[0] += w * w0.x; aw[1] += w * w0.y; aw[2] += w * w0.z; aw[3] += w * w0.w;
    aw[4] += w * w1.x; aw[5] += w * w1.y; aw[6] += w * w1.z; aw[7] += w * w1.w;
    ab[0] += w * b0.x; ab[1] += w * b0.y; ab[2] += w * b0.z; ab[3] += w * b0.w;
    ab[4] += w * b1.x; ab[5] += w * b1.y; ab[6] += w * b1.z; ab[7] += w * b1.w;
  }
  float4* wo = (float4*)(Gw + (size_t)id * Hv);
  wo[0] = make_float4(aw[0], aw[1], aw[2], aw[3]);
  wo[1] = make_float4(aw[4], aw[5], aw[6], aw[7]);
  float4* bo = (float4*)(Gb + (size_t)id * Hv);
  bo[0] = make_float4(ab[0], ab[1], ab[2], ab[3]);
  bo[1] = make_float4(ab[4], ab[5], ab[6], ab[7]);
}

// ---------------- h init: input proj + pos proj; acc = a0 * h
__global__ void k_init(const float* x, const float* posp,
                       const float* iw1, const float* ib1,
                       const float* iw2, const float* ib2,
                       const float* a9, float* hA, float* acc) {
  int t = blockIdx.x * blockDim.x + threadIdx.x;
  if (t >= Bv * Pv * Nv) return;
  float xv = x[t];
  float u[8];
  #pragma unroll
  for (int j = 0; j < 8; ++j) u[j] = fmaxf(xv * iw1[j] + ib1[j], 0.f);
  int n = t % Nv;
  const float4* pp = (const float4*)(posp + (size_t)n * Hv);
  float4 p0 = pp[0], p1 = pp[1];
  float pv[8] = {p0.x, p0.y, p0.z, p0.w, p1.x, p1.y, p1.z, p1.w};
  float a0 = a9[0];
  float o[8];
  #pragma unroll
  for (int ch = 0; ch < 8; ++ch) {
    float s = ib2[ch];
    #pragma unroll
    for (int j = 0; j < 8; ++j) s += u[j] * iw2[j * 8 + ch];
    o[ch] = s + pv[ch];
  }
  float4* hr = (float4*)(hA + (size_t)t * Hv);
  hr[0] = make_float4(o[0], o[1], o[2], o[3]);
  hr[1] = make_float4(o[4], o[5], o[6], o[7]);
  float4* ar = (float4*)(acc + (size_t)t * Hv);
  ar[0] = make_float4(a0 * o[0], a0 * o[1], a0 * o[2], a0 * o[3]);
  ar[1] = make_float4(a0 * o[4], a0 * o[5], a0 * o[6], a0 * o[7]);
}

// block-level reduce of (s1,s2) over 256 threads, then one atomicAdd pair.
// Safe to call repeatedly (trailing barrier). ALL threads must call.
__device__ inline void partial_to_stats(float s1, float s2, float* stats_g) {
  #pragma unroll
  for (int off = 32; off > 0; off >>= 1) {
    s1 += __shfl_down(s1, off, 64);
    s2 += __shfl_down(s2, off, 64);
  }
  __shared__ float r1[4], r2[4];
  int wid = threadIdx.x >> 6, lane = threadIdx.x & 63;
  if (lane == 0) { r1[wid] = s1; r2[wid] = s2; }
  __syncthreads();
  if (threadIdx.x == 0) {
    float a = r1[0] + r1[1] + r1[2] + r1[3];
    float b = r2[0] + r2[1] + r2[2] + r2[3];
    atomicAdd(&stats_g[0], a);
    atomicAdd(&stats_g[1], b);
  }
  __syncthreads();
}

// XCD-locality swizzle: blockIdx%8 = XCD; image g = xcd*12 + local/20 (so XCD x owns batch x)
__device__ inline void img_swizzle(int bx, int& g, int& chunk) {
  int xcd = bx & 7;
  int local = bx >> 3;
  g = xcd * 12 + local / BLKS_PER_IMG;
  chunk = local % BLKS_PER_IMG;
}

// ---------------- stage 1 (used once, i=0): v1 = h + proj(cond); vt = gnw ⊙ v1; stats
__global__ __launch_bounds__(256) void k_stage1(
    const float* __restrict__ h, const float* __restrict__ cond,
    const float* w1, const float* b1, const float* w2, const float* b2,
    const float* __restrict__ gnw,
    float* __restrict__ vt, float* stats1) {
  __shared__ float lw1[64], lw2[64], lb1[8], lb2[8];
  int t = threadIdx.x;
  if (t < 64) lw1[t] = w1[t];
  else if (t < 128) lw2[t - 64] = w2[t - 64];
  else if (t < 136) lb1[t - 128] = b1[t - 128];
  else if (t < 144) lb2[t - 136] = b2[t - 136];
  __syncthreads();
  int g, chunk;
  img_swizzle(blockIdx.x, g, chunk);
  int n = chunk * 256 + t;
  float s1 = 0.f, s2 = 0.f;
  if (n < Nv) {
    size_t row = ((size_t)g * Nv + n) * Hv;
    const float4* cr = (const float4*)(cond + row);
    float4 c0 = cr[0], c1 = cr[1];
    float xc[8] = {c0.x, c0.y, c0.z, c0.w, c1.x, c1.y, c1.z, c1.w};
    float u[8];
    #pragma unroll
    for (int j = 0; j < 8; ++j) {
      float s = lb1[j];
      #pragma unroll
      for (int k = 0; k < 8; ++k) s += xc[k] * lw1[k * 8 + j];
      u[j] = fmaxf(s, 0.f);
    }
    const float4* hr = (const float4*)(h + row);
    float4 h0 = hr[0], h1 = hr[1];
    float hv[8] = {h0.x, h0.y, h0.z, h0.w, h1.x, h1.y, h1.z, h1.w};
    const float4* gr = (const float4*)(gnw + (size_t)n * Hv);
    float4 g0 = gr[0], g1 = gr[1];
    float gv[8] = {g0.x, g0.y, g0.z, g0.w, g1.x, g1.y, g1.z, g1.w};
    float o[8];
    #pragma unroll
    for (int ch = 0; ch < 8; ++ch) {
      float s = lb2[ch];
      #pragma unroll
      for (int j = 0; j < 8; ++j) s += u[j] * lw2[j * 8 + ch];
      float val = s + hv[ch];
      s1 += val; s2 += val * val;
      o[ch] = val * gv[ch];
    }
    float4* vo = (float4*)(vt + row);
    vo[0] = make_float4(o[0], o[1], o[2], o[3]);
    vo[1] = make_float4(o[4], o[5], o[6], o[7]);
  }
  partial_to_stats(s1, s2, stats1 + (size_t)g * 2);
}

// ---------------- stage 2: v2 = rstd*SpMM(vt) - mean*rstd*Gw + Gb + t; stats2
// Per-image grid (1920 blocks, XCD-swizzled). Block stages its contiguous CSR edge
// slice into LDS (coalesced), then inner loop unrolled x4 -> 8 concurrent row loads.
__global__ __launch_bounds__(256) void k_stage2(
    const float* __restrict__ vt, float* __restrict__ v2,
    const int* __restrict__ row_ptr, const float2* __restrict__ epack,
    const float* __restrict__ Gw, const float* __restrict__ Gb,
    const float* __restrict__ stats1, float* stats2,
    const float* __restrict__ tvec) {
  __shared__ float2 se[ECAP];
  int t = threadIdx.x;
  int g, chunk;
  img_swizzle(blockIdx.x, g, chunk);
  int b = g / Pv;
  int nb0 = chunk * 256;
  int nb1 = nb0 + 256; if (nb1 > Nv) nb1 = Nv;
  int eb0 = row_ptr[nb0];
  int eb1 = row_ptr[nb1];
  int cnt = eb1 - eb0;
  const float2* eps;
  int ebase;
  if (cnt <= ECAP) {
    for (int k = t; k < cnt; k += 256) se[k] = epack[eb0 + k];
    eps = se; ebase = eb0;
  } else {
    eps = epack; ebase = 0;   // fallback (never expected: E[cnt]≈2560)
  }
  __syncthreads();
  float mean = stats1[g * 2] * (1.f / 40000.f);
  float m2   = stats1[g * 2 + 1] * (1.f / 40000.f);
  float var  = m2 - mean * mean;
  float rstd = (float)(1.0 / sqrt((double)var + 1e-5));
  float mrs  = mean * rstd;
  int n = nb0 + t;
  float s1 = 0.f, s2 = 0.f;
  if (n < Nv) {
    const float* vtb = vt + (size_t)g * Nv * Hv;
    float a8[8] = {0,0,0,0,0,0,0,0};
    int e0 = row_ptr[n] - ebase, e1 = row_ptr[n + 1] - ebase;
    int e = e0;
    for (; e + 4 <= e1; e += 4) {
      float2 p0 = eps[e], p1 = eps[e+1], p2 = eps[e+2], p3 = eps[e+3];
      const float4* r0 = (const float4*)(vtb + (size_t)__float_as_int(p0.x) * Hv);
      const float4* r1 = (const float4*)(vtb + (size_t)__float_as_int(p1.x) * Hv);
      const float4* r2 = (const float4*)(vtb + (size_t)__float_as_int(p2.x) * Hv);
      const float4* r3 = (const float4*)(vtb + (size_t)__float_as_int(p3.x) * Hv);
      float4 x00 = r0[0], x01 = r0[1];
      float4 x10 = r1[0], x11 = r1[1];
      float4 x20 = r2[0], x21 = r2[1];
      float4 x30 = r3[0], x31 = r3[1];
      a8[0] += p0.y*x00.x + p1.y*x10.x + p2.y*x20.x + p3.y*x30.x;
      a8[1] += p0.y*x00.y + p1.y*x10.y + p2.y*x20.y + p3.y*x30.y;
      a8[2] += p0.y*x00.z + p1.y*x10.z + p2.y*x20.z + p3.y*x30.z;
      a8[3] += p0.y*x00.w + p1.y*x10.w + p2.y*x20.w + p3.y*x30.w;
      a8[4] += p0.y*x01.x + p1.y*x11.x + p2.y*x21.x + p3.y*x31.x;
      a8[5] += p0.y*x01.y + p1.y*x11.y + p2.y*x21.y + p3.y*x31.y;
      a8[6] += p0.y*x01.z + p1.y*x11.z + p2.y*x21.z + p3.y*x31.z;
      a8[7] += p0.y*x01.w + p1.y*x11.w + p2.y*x21.w + p3.y*x31.w;
    }
    for (; e < e1; ++e) {
      float2 ep = eps[e];
      float w = ep.y;
      const float4* sr = (const float4*)(vtb + (size_t)__float_as_int(ep.x) * Hv);
      float4 x0 = sr[0], x1 = sr[1];
      a8[0] += w*x0.x; a8[1] += w*x0.y; a8[2] += w*x0.z; a8[3] += w*x0.w;
      a8[4] += w*x1.x; a8[5] += w*x1.y; a8[6] += w*x1.z; a8[7] += w*x1.w;
    }
    size_t noff = (size_t)n * Hv;
    const float4* wr = (const float4*)(Gw + noff);
    const float4* br = (const float4*)(Gb + noff);
    float4 w0 = wr[0], w1 = wr[1], b0 = br[0], b1 = br[1];
    float gw8[8] = {w0.x, w0.y, w0.z, w0.w, w1.x, w1.y, w1.z, w1.w};
    float gb8[8] = {b0.x, b0.y, b0.z, b0.w, b1.x, b1.y, b1.z, b1.w};
    float o[8];
    #pragma unroll
    for (int ch = 0; ch < 8; ++ch) {
      float val = rstd * a8[ch] - mrs * gw8[ch] + gb8[ch] + tvec[b * Hv + ch];
      o[ch] = val;
      s1 += val; s2 += val * val;
    }
    float4* vo = (float4*)(v2 + (size_t)g * Nv * Hv + noff);
    vo[0] = make_float4(o[0], o[1], o[2], o[3]);
    vo[1] = make_float4(o[4], o[5], o[6], o[7]);
  }
  partial_to_stats(s1, s2, stats2 + (size_t)g * 2);
}

// ---------------- fused: stage3(i) [LN + conv + skip acc] + stage1(i+1) [cond proj + stats]
// grid: 8 * 40 blocks; blockIdx&7 = b (XCD b owns batch b); thread -> (n, c4 half)
__global__ __launch_bounds__(256) void k_fused31(
    const float* __restrict__ v2, float* __restrict__ acc,
    const float* __restrict__ cond,
    const float* __restrict__ stats2,
    const float* __restrict__ tnw, const float* __restrict__ tnb,
    const float* __restrict__ cw, const float* __restrict__ cb,
    const float* w1, const float* b1, const float* w2, const float* b2, // bc[i+1]
    const float* __restrict__ gnw,                                     // gn_w[i+1]
    float* __restrict__ vt, float* stats1,                             // outputs i+1
    const float* __restrict__ a9, int iblk) {
  __shared__ float scw[144], scb[12], smean[12], srstd[12];
  __shared__ float lw1[64], lw2[64], lb1[8], lb2[8];
  int t = threadIdx.x;
  int b = blockIdx.x & 7;
  int chunk = blockIdx.x >> 3;
  if (t < 144) scw[t] = cw[t];
  else if (t < 156) scb[t - 144] = cb[t - 144];
  else if (t < 168) {
    int p = t - 156;
    int g = b * Pv + p;
    float mean = stats2[g * 2] * (1.f / 40000.f);
    float m2   = stats2[g * 2 + 1] * (1.f / 40000.f);
    float var  = m2 - mean * mean;
    smean[p] = mean;
    srstd[p] = (float)(1.0 / sqrt((double)var + 1e-5));
  }
  if (t < 64) lw1[t] = w1[t];
  else if (t < 128) lw2[t - 64] = w2[t - 64];
  else if (t < 136) lb1[t - 128] = b1[t - 128];
  else if (t < 144) lb2[t - 136] = b2[t - 136];
  __syncthreads();
  int idx = chunk * 256 + t;
  bool active = idx < Nv * 2;
  float s1a[12], s2a[12];
  #pragma unroll
  for (int p = 0; p < 12; ++p) { s1a[p] = 0.f; s2a[p] = 0.f; }
  if (active) {
    int n = idx >> 1, c4 = idx & 1;
    size_t noff = (size_t)n * Hv + c4 * 4;
    const float4 w4 = *(const float4*)(tnw + noff);
    const float4 b4 = *(const float4*)(tnb + noff);
    const float4 gv = *(const float4*)(gnw + noff);
    size_t strideP = (size_t)Nv * Hv;
    size_t base = (size_t)b * Pv * strideP + noff;
    float4 in[12];
    #pragma unroll
    for (int p = 0; p < 12; ++p) {
      float4 v = *(const float4*)(v2 + base + p * strideP);
      float mean = smean[p], rstd = srstd[p];
      in[p].x = (v.x - mean) * rstd * w4.x + b4.x;
      in[p].y = (v.y - mean) * rstd * w4.y + b4.y;
      in[p].z = (v.z - mean) * rstd * w4.z + b4.z;
      in[p].w = (v.w - mean) * rstd * w4.w + b4.w;
    }
    float ai = a9[iblk + 1];
    #pragma unroll
    for (int q = 0; q < 12; ++q) {
      // conv output (skip[i+1] value), this thread's 4 channels
      float4 o = make_float4(scb[q], scb[q], scb[q], scb[q]);
      #pragma unroll
      for (int p = 0; p < 12; ++p) {
        float c = scw[q * 12 + p];
        o.x += c * in[p].x; o.y += c * in[p].y;
        o.z += c * in[p].z; o.w += c * in[p].w;
      }
      size_t off = base + q * strideP;
      // skip accumulate
      float4* ap = (float4*)(acc + off);
      float4 av = *ap;
      av.x += ai * o.x; av.y += ai * o.y; av.z += ai * o.z; av.w += ai * o.w;
      *ap = av;
      // cond projection (stage1 of i+1): need full 8-ch cond row; pair-exchange halves
      float4 cme = *(const float4*)(cond + off);
      float c8[8];
      float e0 = __shfl_xor(cme.x, 1, 64);
      float e1 = __shfl_xor(cme.y, 1, 64);
      float e2 = __shfl_xor(cme.z, 1, 64);
      float e3 = __shfl_xor(cme.w, 1, 64);
      if (c4 == 0) {
        c8[0] = cme.x; c8[1] = cme.y; c8[2] = cme.z; c8[3] = cme.w;
        c8[4] = e0; c8[5] = e1; c8[6] = e2; c8[7] = e3;
      } else {
        c8[0] = e0; c8[1] = e1; c8[2] = e2; c8[3] = e3;
        c8[4] = cme.x; c8[5] = cme.y; c8[6] = cme.z; c8[7] = cme.w;
      }
      float u8[8];
      #pragma unroll
      for (int j = 0; j < 8; ++j) {
        float s = lb1[j];
        #pragma unroll
        for (int k = 0; k < 8; ++k) s += c8[k] * lw1[k * 8 + j];
        u8[j] = fmaxf(s, 0.f);
      }
      float val[4];
      #pragma unroll
      for (int m = 0; m < 4; ++m) {
        int ch = c4 * 4 + m;
        float s = lb2[ch];
        #pragma unroll
        for (int j = 0; j < 8; ++j) s += u8[j] * lw2[j * 8 + ch];
        val[m] = s;
      }
      val[0] += o.x; val[1] += o.y; val[2] += o.z; val[3] += o.w;
      s1a[q] += val[0] + val[1] + val[2] + val[3];
      s2a[q] += val[0]*val[0] + val[1]*val[1] + val[2]*val[2] + val[3]*val[3];
      // vt = gn_w[i+1] ⊙ (h + c)
      *(float4*)(vt + off) = make_float4(val[0]*gv.x, val[1]*gv.y,
                                         val[2]*gv.z, val[3]*gv.w);
    }
  }
  #pragma unroll
  for (int p = 0; p < 12; ++p)
    partial_to_stats(s1a[p], s2a[p], stats1 + (size_t)(b * Pv + p) * 2);
}

// ---------------- stage 3 (final block only): LN + conv + skip acc
__global__ __launch_bounds__(256) void k_stage3(
    float* __restrict__ v2, float* __restrict__ acc,
    const float* __restrict__ stats2,
    const float* __restrict__ tnw, const float* __restrict__ tnb,
    const float* __restrict__ cw, const float* __restrict__ cb,
    const float* __restrict__ a9, int iblk) {
  __shared__ float scw[144], scb[12], smean[12], srstd[12];
  int t = threadIdx.x;
  int b = blockIdx.x & 7;
  int chunk = blockIdx.x >> 3;
  if (t < 144) scw[t] = cw[t];
  else if (t < 156) scb[t - 144] = cb[t - 144];
  else if (t < 168) {
    int p = t - 156;
    int g = b * Pv + p;
    float mean = stats2[g * 2] * (1.f / 40000.f);
    float m2   = stats2[g * 2 + 1] * (1.f / 40000.f);
    float var  = m2 - mean * mean;
    smean[p] = mean;
    srstd[p] = (float)(1.0 / sqrt((double)var + 1e-5));
  }
  __syncthreads();
  int idx = chunk * 256 + t;
  if (idx >= Nv * 2) return;
  int n = idx >> 1, c4 = idx & 1;
  size_t noff = (size_t)n * Hv + c4 * 4;
  const float4 w4 = *(const float4*)(tnw + noff);
  const float4 b4 = *(const float4*)(tnb + noff);
  size_t strideP = (size_t)Nv * Hv;
  size_t base = (size_t)b * Pv * strideP + noff;
  float4 in[12];
  #pragma unroll
  for (int p = 0; p < 12; ++p) {
    float4 v = *(const float4*)(v2 + base + p * strideP);
    float mean = smean[p], rstd = srstd[p];
    in[p].x = (v.x - mean) * rstd * w4.x + b4.x;
    in[p].y = (v.y - mean) * rstd * w4.y + b4.y;
    in[p].z = (v.z - mean) * rstd * w4.z + b4.z;
    in[p].w = (v.w - mean) * rstd * w4.w + b4.w;
  }
  float ai = a9[iblk + 1];
  #pragma unroll
  for (int q = 0; q < 12; ++q) {
    float4 o = make_float4(scb[q], scb[q], scb[q], scb[q]);
    #pragma unroll
    for (int p = 0; p < 12; ++p) {
      float c = scw[q * 12 + p];
      o.x += c * in[p].x; o.y += c * in[p].y;
      o.z += c * in[p].z; o.w += c * in[p].w;
    }
    size_t off = base + q * strideP;
    float4* ap = (float4*)(acc + off);
    float4 av = *ap;
    av.x += ai * o.x; av.y += ai * o.y; av.z += ai * o.z; av.w += ai * o.w;
    *ap = av;
  }
}

// ---------------- output projection
__global__ void k_out(const float* acc, const float* ow1, const float* ob1,
                      const float* ow2, const float* ob2, float* out) {
  int t = blockIdx.x * blockDim.x + threadIdx.x;
  if (t >= Bv * Pv * Nv) return;
  const float4* ar = (const float4*)(acc + (size_t)t * Hv);
  float4 a0 = ar[0], a1 = ar[1];
  float x[8] = {a0.x, a0.y, a0.z, a0.w, a1.x, a1.y, a1.z, a1.w};
  float o = ob2[0];
  #pragma unroll
  for (int j = 0; j < 8; ++j) {
    float s = ob1[j];
    #pragma unroll
    for (int k = 0; k < 8; ++k) s += x[k] * ow1[k * 8 + j];
    o += fmaxf(s, 0.f) * ow2[j];
  }
  out[t] = o;
}

extern "C" void kernel_launch(void* const* d_in, const int* in_sizes, int n_in,
                              void* d_out, int out_size, void* d_ws, size_t ws_size,
                              hipStream_t stream) {
  const float* x      = (const float*)d_in[0];
  const float* cond   = (const float*)d_in[1];
  const float* pos    = (const float*)d_in[2];
  const int*   timei  = (const int*)  d_in[3];
  const int*   eidx   = (const int*)  d_in[4];
  const float* te_w1  = (const float*)d_in[5];
  const float* te_b1  = (const float*)d_in[6];
  const float* te_w2  = (const float*)d_in[7];
  const float* te_b2  = (const float*)d_in[8];
  const float* in_w1  = (const float*)d_in[9];
  const float* in_b1  = (const float*)d_in[10];
  const float* in_w2  = (const float*)d_in[11];
  const float* in_b2  = (const float*)d_in[12];
  const float* pos_w1 = (const float*)d_in[13];
  const float* pos_b1 = (const float*)d_in[14];
  const float* pos_w2 = (const float*)d_in[15];
  const float* pos_b2 = (const float*)d_in[16];
  const float* attn   = (const float*)d_in[17];
  const float* bt_w1  = (const float*)d_in[18];
  const float* bt_b1  = (const float*)d_in[19];
  const float* bt_w2  = (const float*)d_in[20];
  const float* bt_b2  = (const float*)d_in[21];
  const float* bc_w1  = (const float*)d_in[22];
  const float* bc_b1  = (const float*)d_in[23];
  const float* bc_w2  = (const float*)d_in[24];
  const float* bc_b2  = (const float*)d_in[25];
  const float* gn_w   = (const float*)d_in[26];
  const float* gn_b   = (const float*)d_in[27];
  const float* tn_w   = (const float*)d_in[28];
  const float* tn_b   = (const float*)d_in[29];
  const float* cv_w   = (const float*)d_in[30];
  const float* cv_b   = (const float*)d_in[31];
  const float* out_w1 = (const float*)d_in[32];
  const float* out_b1 = (const float*)d_in[33];
  const float* out_w2 = (const float*)d_in[34];
  const float* out_b2 = (const float*)d_in[35];
  float* out = (float*)d_out;

  const size_t HSZ = (size_t)Bv * Pv * Nv * Hv;  // 3,840,000
  float* ws    = (float*)d_ws;
  float* X     = ws;                 // v2 buffer
  float* Y     = X + HSZ;            // vt (= gnw ⊙ v1) buffer
  float* acc   = Y + HSZ;
  float* posp  = acc + HSZ;          // Nv*Hv
  float* deg   = posp + Nv * Hv;     // Nv
  float* dinv  = deg + Nv;           // Nv
  float* epack = dinv + Nv;          // 2*Ev floats
  float* t_all = epack + 2 * Ev;     // NBv*Bv*Hv = 512
  float* a9    = t_all + NBv * Bv * Hv;  // 16
  float* stats = a9 + 16;            // NBv*2*NIMG*2 = 3072
  float* Gw    = stats + NBv * 2 * NIMG * 2;  // NBv*Nv*Hv = 320000
  float* Gb    = Gw + NBv * Nv * Hv;          // 320000
  int* row_ptr = (int*)(Gb + NBv * Nv * Hv);  // Nv+8
  int* cursor  = row_ptr + Nv + 8;   // Nv+8

  k_setup<<<1, 64, 0, stream>>>(timei, attn, te_w1, te_b1, te_w2, te_b2,
                                bt_w1, bt_b1, bt_w2, bt_b2, t_all, a9);
  k_posp<<<(Nv + 255) / 256, 256, 0, stream>>>(pos, pos_w1, pos_b1, pos_w2, pos_b2, posp);
  k_zero<<<(Nv + 255) / 256, 256, 0, stream>>>(deg, cursor, stats);
  k_deg<<<(Ev + 255) / 256, 256, 0, stream>>>(eidx, deg);
  k_dinv<<<(Nv + 255) / 256, 256, 0, stream>>>(deg, dinv);
  k_scan<<<1, 1024, 0, stream>>>(deg, row_ptr);
  k_csr<<<(Ev + 255) / 256, 256, 0, stream>>>(eidx, dinv, row_ptr, cursor, (float2*)epack);
  k_gwb<<<(NBv * Nv + 255) / 256, 256, 0, stream>>>(
      row_ptr, (const float2*)epack, gn_w, gn_b, Gw, Gb);
  k_init<<<(Bv * Pv * Nv + 255) / 256, 256, 0, stream>>>(
      x, posp, in_w1, in_b1, in_w2, in_b2, a9, X, acc);

  // stage1 for i=0
  k_stage1<<<NIMG * BLKS_PER_IMG, 256, 0, stream>>>(
      X, cond, bc_w1, bc_b1, bc_w2, bc_b2, gn_w, Y,
      stats + 0);

  for (int i = 0; i < NBv; ++i) {
    float* st1 = stats + (size_t)(i * 2 + 0) * NIMG * 2;
    float* st2 = stats + (size_t)(i * 2 + 1) * NIMG * 2;
    k_stage2<<<NIMG * BLKS_PER_IMG, 256, 0, stream>>>(
        Y, X, row_ptr, (const float2*)epack,
        Gw + (size_t)i * Nv * Hv, Gb + (size_t)i * Nv * Hv,
        st1, st2, t_all + i * Bv * Hv);
    if (i < NBv - 1) {
      float* st1n = stats + (size_t)((i + 1) * 2 + 0) * NIMG * 2;
      k_fused31<<<8 * 40, 256, 0, stream>>>(
          X, acc, cond, st2,
          tn_w + (size_t)i * Nv * Hv, tn_b + (size_t)i * Nv * Hv,
          cv_w + i * 144, cv_b + i * 12,
          bc_w1 + (i + 1) * 64, bc_b1 + (i + 1) * 8,
          bc_w2 + (i + 1) * 64, bc_b2 + (i + 1) * 8,
          gn_w + (size_t)(i + 1) * Nv * Hv,
          Y, st1n, a9, i);
    } else {
      k_stage3<<<8 * 40, 256, 0, stream>>>(
          X, acc, st2,
          tn_w + (size_t)i * Nv * Hv, tn_b + (size_t)i * Nv * Hv,
          cv_w + i * 144, cv_b + i * 12, a9, i);
    }
  }
  k_out<<<(Bv * Pv * Nv + 255) / 256, 256, 0, stream>>>(
      acc, out_w1, out_b1, out_w2, out_b2, out);
}

// Round 10
// 639.001 us; speedup vs baseline: 1.4992x; 1.4992x over previous
//
#include <hip/hip_runtime.h>
#include <math.h>

#define Bv 8
#define Pv 12
#define Nv 5000
#define Hv 8
#define Ev 50000
#define NBv 8
#define TD1v 64
#define NIMG (Bv * Pv)          // 96 images
#define BLKS_PER_IMG 20         // ceil(5000/256)
#define ECAP 3072               // LDS edge-stage capacity (24 KB -> 6 blocks/CU)

typedef float f4v __attribute__((ext_vector_type(4)));

__device__ inline float4 nt_load4(const float* p) {
  f4v v = __builtin_nontemporal_load((const f4v*)p);
  return make_float4(v.x, v.y, v.z, v.w);
}
__device__ inline void nt_store4(float* p, float a, float b, float c, float d) {
  f4v v = {a, b, c, d};
  __builtin_nontemporal_store(v, (f4v*)p);
}

// correctly-rounded f32 of 10^(d/4), d=0..15 (matches numpy float32 powf)
__device__ __constant__ float POW10Q[16] = {
  1.0f, 1.7782794100389228f, 3.1622776601683795f, 5.623413251903491f,
  10.0f, 17.78279410038923f, 31.622776601683793f, 56.23413251903491f,
  100.0f, 177.82794100389228f, 316.22776601683796f, 562.341325190349f,
  1000.0f, 1778.2794100389228f, 3162.2776601683795f, 5623.413251903491f
};

// ---------------- setup: time-embedding chain, per-block t vectors, softmax(attn)
__global__ void k_setup(const int* timei, const float* attn,
                        const float* te_w1, const float* te_b1,
                        const float* te_w2, const float* te_b2,
                        const float* bt_w1, const float* bt_b1,
                        const float* bt_w2, const float* bt_b2,
                        float* t_all, float* a9) {
  __shared__ float te0[Bv][32];
  __shared__ float te1[Bv][64];
  __shared__ float te2[Bv][64];
  int t = threadIdx.x; // 64 threads
  for (int idx = t; idx < Bv * 16; idx += 64) {
    int b = idx >> 4, d = idx & 15;
    float e = (float)timei[b] * POW10Q[d];        // f32 rounding as in numpy
    te0[b][d]      = (float)sin((double)e);        // accurate sin at the f32 arg
    te0[b][d + 16] = (float)cos((double)e);
  }
  __syncthreads();
  for (int idx = t; idx < Bv * 64; idx += 64) {
    int b = idx >> 6, j = idx & 63;
    float s = te_b1[j];
    for (int k = 0; k < 32; ++k) s += te0[b][k] * te_w1[k * 64 + j];
    te1[b][j] = s / (1.0f + expf(-s));             // silu
  }
  __syncthreads();
  for (int idx = t; idx < Bv * 64; idx += 64) {
    int b = idx >> 6, j = idx & 63;
    float s = te_b2[j];
    for (int k = 0; k < 64; ++k) s += te1[b][k] * te_w2[k * 64 + j];
    te2[b][j] = s / (1.0f + expf(-s));
  }
  __syncthreads();
  {
    int i = t >> 3, b = t & 7;  // 64 (block,batch) pairs
    float u[Hv];
    for (int j = 0; j < Hv; ++j) {
      float s = bt_b1[i * Hv + j];
      for (int k = 0; k < TD1v; ++k) s += te2[b][k] * bt_w1[(i * TD1v + k) * Hv + j];
      u[j] = fmaxf(s, 0.0f);
    }
    for (int ch = 0; ch < Hv; ++ch) {
      float s = bt_b2[i * Hv + ch];
      for (int j = 0; j < Hv; ++j) s += u[j] * bt_w2[(i * Hv + j) * Hv + ch];
      t_all[(i * Bv + b) * Hv + ch] = s;
    }
  }
  if (t == 0) {
    float m = attn[0];
    for (int i = 1; i < 9; ++i) m = fmaxf(m, attn[i]);
    float s = 0.f, ex[9];
    for (int i = 0; i < 9; ++i) { ex[i] = expf(attn[i] - m); s += ex[i]; }
    for (int i = 0; i < 9; ++i) a9[i] = ex[i] / s;
  }
}

// ---------------- positional projection, once: posp[n][ch]
__global__ void k_posp(const float* pos, const float* pw1, const float* pb1,
                       const float* pw2, const float* pb2, float* posp) {
  int n = blockIdx.x * blockDim.x + threadIdx.x;
  if (n >= Nv) return;
  const float4* pr = (const float4*)(pos + (size_t)n * Hv);
  float4 r0 = pr[0], r1 = pr[1];
  float x[8] = {r0.x, r0.y, r0.z, r0.w, r1.x, r1.y, r1.z, r1.w};
  float u[8];
  #pragma unroll
  for (int j = 0; j < 8; ++j) {
    float s = pb1[j];
    #pragma unroll
    for (int k = 0; k < 8; ++k) s += x[k] * pw1[k * 8 + j];
    u[j] = fmaxf(s, 0.f);
  }
  float o[8];
  #pragma unroll
  for (int ch = 0; ch < 8; ++ch) {
    float s = pb2[ch];
    #pragma unroll
    for (int j = 0; j < 8; ++j) s += u[j] * pw2[j * 8 + ch];
    o[ch] = s;
  }
  float4* po = (float4*)(posp + (size_t)n * Hv);
  po[0] = make_float4(o[0], o[1], o[2], o[3]);
  po[1] = make_float4(o[4], o[5], o[6], o[7]);
}

// zero deg/cursor + all stats slots
__global__ void k_zero(float* deg, int* cursor, float* stats) {
  int i = blockIdx.x * blockDim.x + threadIdx.x;
  if (i < Nv) { deg[i] = 0.f; cursor[i] = 0; }
  if (i < NBv * 2 * NIMG * 2) stats[i] = 0.f;
}

__global__ void k_deg(const int* eidx, float* deg) {
  int e = blockIdx.x * blockDim.x + threadIdx.x;
  if (e < Ev) atomicAdd(&deg[eidx[Ev + e]], 1.0f);
}

__global__ void k_dinv(const float* deg, float* dinv) {
  int n = blockIdx.x * blockDim.x + threadIdx.x;
  if (n < Nv) {
    float d = deg[n];
    dinv[n] = d > 0.f ? (float)(1.0 / sqrt((double)d)) : 0.f;
  }
}

// single-block Hillis-Steele scan of per-dst counts -> row_ptr[0..Nv]
__global__ void k_scan(const float* deg, int* row_ptr) {
  __shared__ int buf[1024];
  __shared__ int base_s;
  int t = threadIdx.x;
  if (t == 0) { base_s = 0; row_ptr[0] = 0; }
  __syncthreads();
  for (int c = 0; c < 5; ++c) {
    int i = c * 1024 + t;
    int v = (i < Nv) ? (int)(deg[i] + 0.5f) : 0;
    buf[t] = v;
    __syncthreads();
    for (int off = 1; off < 1024; off <<= 1) {
      int add = (t >= off) ? buf[t - off] : 0;
      __syncthreads();
      buf[t] += add;
      __syncthreads();
    }
    int base = base_s;
    if (i < Nv) row_ptr[i + 1] = base + buf[t];
    __syncthreads();
    if (t == 1023) base_s = base + buf[1023];
    __syncthreads();
  }
}

// CSR fill: packed (src_bits, w) per edge
__global__ void k_csr(const int* eidx, const float* dinv, const int* row_ptr,
                      int* cursor, float2* epack) {
  int e = blockIdx.x * blockDim.x + threadIdx.x;
  if (e >= Ev) return;
  int s = eidx[e], d = eidx[Ev + e];
  int slot = atomicAdd(&cursor[d], 1);
  int pos = row_ptr[d] + slot;
  epack[pos] = make_float2(__int_as_float(s), dinv[s] * dinv[d]);
}

// ---------------- per block-iter, image-independent: Gw[i][n]=Σ w_e gnw_i[src], Gb likewise
__global__ __launch_bounds__(256) void k_gwb(
    const int* __restrict__ row_ptr, const float2* __restrict__ epack,
    const float* __restrict__ gn_w, const float* __restrict__ gn_b,
    float* __restrict__ Gw, float* __restrict__ Gb) {
  int id = blockIdx.x * 256 + threadIdx.x;
  if (id >= NBv * Nv) return;
  int i = id / Nv, n = id % Nv;
  const float* gw = gn_w + (size_t)i * Nv * Hv;
  const float* gb = gn_b + (size_t)i * Nv * Hv;
  float aw[8] = {0,0,0,0,0,0,0,0}, ab[8] = {0,0,0,0,0,0,0,0};
  int e0 = row_ptr[n], e1 = row_ptr[n + 1];
  for (int e = e0; e < e1; ++e) {
    float2 ep = epack[e];
    int s = __float_as_int(ep.x);
    float w = ep.y;
    const float4* wr = (const float4*)(gw + (size_t)s * Hv);
    const float4* br = (const float4*)(gb + (size_t)s * Hv);
    float4 w0 = wr[0], w1 = wr[1], b0 = br[0], b1 = br[1];
    aw[0] += w * w0.x; aw[1] += w * w0.y; aw[2] += w * w0.z; aw[3] += w * w0.w;
    aw[4] += w * w1.x; aw[5] += w * w1.y; aw[6] += w * w1.z; aw[7] += w * w1.w;
    ab[0] += w * b0.x; ab[1] += w * b0.y; ab[2] += w * b0.z; ab[3] += w * b0.w;
    ab[4] += w * b1.x; ab[5] += w * b1.y; ab[6] += w * b1.z; ab[7] += w * b1.w;
  }
  float4* wo = (float4*)(Gw + (size_t)id * Hv);
  wo[0] = make_float4(aw[0], aw[1], aw[2], aw[3]);
  wo[1] = make_float4(aw[4], aw[5], aw[6], aw[7]);
  float4* bo = (float4*)(Gb + (size_t)id * Hv);
  bo[0] = make_float4(ab[0], ab[1], ab[2], ab[3]);
  bo[1] = make_float4(ab[4], ab[5], ab[6], ab[7]);
}

// ---------------- h init: input proj + pos proj; acc = a0 * h
__global__ void k_init(const float* x, const float* posp,
                       const float* iw1, const float* ib1,
                       const float* iw2, const float* ib2,
                       const float* a9, float* hA, float* acc) {
  int t = blockIdx.x * blockDim.x + threadIdx.x;
  if (t >= Bv * Pv * Nv) return;
  float xv = __builtin_nontemporal_load(x + t);
  float u[8];
  #pragma unroll
  for (int j = 0; j < 8; ++j) u[j] = fmaxf(xv * iw1[j] + ib1[j], 0.f);
  int n = t % Nv;
  const float4* pp = (const float4*)(posp + (size_t)n * Hv);
  float4 p0 = pp[0], p1 = pp[1];
  float pv[8] = {p0.x, p0.y, p0.z, p0.w, p1.x, p1.y, p1.z, p1.w};
  float a0 = a9[0];
  float o[8];
  #pragma unroll
  for (int ch = 0; ch < 8; ++ch) {
    float s = ib2[ch];
    #pragma unroll
    for (int j = 0; j < 8; ++j) s += u[j] * iw2[j * 8 + ch];
    o[ch] = s + pv[ch];
  }
  float4* hr = (float4*)(hA + (size_t)t * Hv);
  hr[0] = make_float4(o[0], o[1], o[2], o[3]);
  hr[1] = make_float4(o[4], o[5], o[6], o[7]);
  nt_store4(acc + (size_t)t * Hv,     a0 * o[0], a0 * o[1], a0 * o[2], a0 * o[3]);
  nt_store4(acc + (size_t)t * Hv + 4, a0 * o[4], a0 * o[5], a0 * o[6], a0 * o[7]);
}

// block-level reduce of (s1,s2) over 256 threads, then one atomicAdd pair.
__device__ inline void partial_to_stats(float s1, float s2, float* stats_g) {
  #pragma unroll
  for (int off = 32; off > 0; off >>= 1) {
    s1 += __shfl_down(s1, off, 64);
    s2 += __shfl_down(s2, off, 64);
  }
  __shared__ float r1[4], r2[4];
  int wid = threadIdx.x >> 6, lane = threadIdx.x & 63;
  if (lane == 0) { r1[wid] = s1; r2[wid] = s2; }
  __syncthreads();
  if (threadIdx.x == 0) {
    float a = r1[0] + r1[1] + r1[2] + r1[3];
    float b = r2[0] + r2[1] + r2[2] + r2[3];
    atomicAdd(&stats_g[0], a);
    atomicAdd(&stats_g[1], b);
  }
  __syncthreads();
}

// XCD-locality swizzle: blockIdx%8 = XCD; image g = xcd*12 + local/20 (XCD x owns batch x)
__device__ inline void img_swizzle(int bx, int& g, int& chunk) {
  int xcd = bx & 7;
  int local = bx >> 3;
  g = xcd * 12 + local / BLKS_PER_IMG;
  chunk = local % BLKS_PER_IMG;
}

// ---------------- stage 1: v1 = h + proj(cond); write vt = gnw ⊙ v1; stats over v1
__global__ __launch_bounds__(256) void k_stage1(
    const float* __restrict__ h, const float* __restrict__ cond,
    const float* w1, const float* b1, const float* w2, const float* b2,
    const float* __restrict__ gnw,
    float* __restrict__ vt, float* stats1) {
  __shared__ float lw1[64], lw2[64], lb1[8], lb2[8];
  int t = threadIdx.x;
  if (t < 64) lw1[t] = w1[t];
  else if (t < 128) lw2[t - 64] = w2[t - 64];
  else if (t < 136) lb1[t - 128] = b1[t - 128];
  else if (t < 144) lb2[t - 136] = b2[t - 136];
  __syncthreads();
  int g, chunk;
  img_swizzle(blockIdx.x, g, chunk);
  int n = chunk * 256 + t;
  float s1 = 0.f, s2 = 0.f;
  if (n < Nv) {
    size_t row = ((size_t)g * Nv + n) * Hv;
    float4 c0 = nt_load4(cond + row);       // single-use stream: keep out of L2
    float4 c1 = nt_load4(cond + row + 4);
    float xc[8] = {c0.x, c0.y, c0.z, c0.w, c1.x, c1.y, c1.z, c1.w};
    float u[8];
    #pragma unroll
    for (int j = 0; j < 8; ++j) {
      float s = lb1[j];
      #pragma unroll
      for (int k = 0; k < 8; ++k) s += xc[k] * lw1[k * 8 + j];
      u[j] = fmaxf(s, 0.f);
    }
    const float4* hr = (const float4*)(h + row);
    float4 h0 = hr[0], h1 = hr[1];
    float hv[8] = {h0.x, h0.y, h0.z, h0.w, h1.x, h1.y, h1.z, h1.w};
    const float4* gr = (const float4*)(gnw + (size_t)n * Hv);
    float4 g0 = gr[0], g1 = gr[1];
    float gv[8] = {g0.x, g0.y, g0.z, g0.w, g1.x, g1.y, g1.z, g1.w};
    float o[8];
    #pragma unroll
    for (int ch = 0; ch < 8; ++ch) {
      float s = lb2[ch];
      #pragma unroll
      for (int j = 0; j < 8; ++j) s += u[j] * lw2[j * 8 + ch];
      float val = s + hv[ch];
      s1 += val; s2 += val * val;
      o[ch] = val * gv[ch];          // pre-scale by gn_w for the SpMM
    }
    float4* vo = (float4*)(vt + row);     // gather target: keep IN L2 (normal store)
    vo[0] = make_float4(o[0], o[1], o[2], o[3]);
    vo[1] = make_float4(o[4], o[5], o[6], o[7]);
  }
  partial_to_stats(s1, s2, stats1 + (size_t)g * 2);
}

// ---------------- stage 2: v2 = rstd*SpMM(vt) - mean*rstd*Gw + Gb + t; stats2
// Per-image grid (1920 blocks, XCD-swizzled). Block stages its contiguous CSR edge
// slice into LDS; inner loop unrolled x4 -> 8 concurrent row gathers; v2 nt-stored.
__global__ __launch_bounds__(256) void k_stage2(
    const float* __restrict__ vt, float* __restrict__ v2,
    const int* __restrict__ row_ptr, const float2* __restrict__ epack,
    const float* __restrict__ Gw, const float* __restrict__ Gb,
    const float* __restrict__ stats1, float* stats2,
    const float* __restrict__ tvec) {
  __shared__ float2 se[ECAP];
  int t = threadIdx.x;
  int g, chunk;
  img_swizzle(blockIdx.x, g, chunk);
  int b = g / Pv;
  int nb0 = chunk * 256;
  int nb1 = nb0 + 256; if (nb1 > Nv) nb1 = Nv;
  int eb0 = row_ptr[nb0];
  int eb1 = row_ptr[nb1];
  int cnt = eb1 - eb0;
  const float2* eps;
  int ebase;
  if (cnt <= ECAP) {
    for (int k = t; k < cnt; k += 256) se[k] = epack[eb0 + k];
    eps = se; ebase = eb0;
  } else {
    eps = epack; ebase = 0;   // fallback (expected cnt ~2560 +- 50)
  }
  __syncthreads();
  float mean = stats1[g * 2] * (1.f / 40000.f);
  float m2   = stats1[g * 2 + 1] * (1.f / 40000.f);
  float var  = m2 - mean * mean;
  float rstd = (float)(1.0 / sqrt((double)var + 1e-5));
  float mrs  = mean * rstd;
  int n = nb0 + t;
  float s1 = 0.f, s2 = 0.f;
  if (n < Nv) {
    const float* vtb = vt + (size_t)g * Nv * Hv;
    float a8[8] = {0,0,0,0,0,0,0,0};
    int e0 = row_ptr[n] - ebase, e1 = row_ptr[n + 1] - ebase;
    int e = e0;
    for (; e + 4 <= e1; e += 4) {
      float2 p0 = eps[e], p1 = eps[e+1], p2 = eps[e+2], p3 = eps[e+3];
      const float4* r0 = (const float4*)(vtb + (size_t)__float_as_int(p0.x) * Hv);
      const float4* r1 = (const float4*)(vtb + (size_t)__float_as_int(p1.x) * Hv);
      const float4* r2 = (const float4*)(vtb + (size_t)__float_as_int(p2.x) * Hv);
      const float4* r3 = (const float4*)(vtb + (size_t)__float_as_int(p3.x) * Hv);
      float4 x00 = r0[0], x01 = r0[1];
      float4 x10 = r1[0], x11 = r1[1];
      float4 x20 = r2[0], x21 = r2[1];
      float4 x30 = r3[0], x31 = r3[1];
      a8[0] += p0.y*x00.x + p1.y*x10.x + p2.y*x20.x + p3.y*x30.x;
      a8[1] += p0.y*x00.y + p1.y*x10.y + p2.y*x20.y + p3.y*x30.y;
      a8[2] += p0.y*x00.z + p1.y*x10.z + p2.y*x20.z + p3.y*x30.z;
      a8[3] += p0.y*x00.w + p1.y*x10.w + p2.y*x20.w + p3.y*x30.w;
      a8[4] += p0.y*x01.x + p1.y*x11.x + p2.y*x21.x + p3.y*x31.x;
      a8[5] += p0.y*x01.y + p1.y*x11.y + p2.y*x21.y + p3.y*x31.y;
      a8[6] += p0.y*x01.z + p1.y*x11.z + p2.y*x21.z + p3.y*x31.z;
      a8[7] += p0.y*x01.w + p1.y*x11.w + p2.y*x21.w + p3.y*x31.w;
    }
    for (; e < e1; ++e) {
      float2 ep = eps[e];
      float w = ep.y;
      const float4* sr = (const float4*)(vtb + (size_t)__float_as_int(ep.x) * Hv);
      float4 x0 = sr[0], x1 = sr[1];
      a8[0] += w*x0.x; a8[1] += w*x0.y; a8[2] += w*x0.z; a8[3] += w*x0.w;
      a8[4] += w*x1.x; a8[5] += w*x1.y; a8[6] += w*x1.z; a8[7] += w*x1.w;
    }
    size_t noff = (size_t)n * Hv;
    const float4* wr = (const float4*)(Gw + noff);
    const float4* br = (const float4*)(Gb + noff);
    float4 w0 = wr[0], w1 = wr[1], b0 = br[0], b1 = br[1];
    float gw8[8] = {w0.x, w0.y, w0.z, w0.w, w1.x, w1.y, w1.z, w1.w};
    float gb8[8] = {b0.x, b0.y, b0.z, b0.w, b1.x, b1.y, b1.z, b1.w};
    float o[8];
    #pragma unroll
    for (int ch = 0; ch < 8; ++ch) {
      float val = rstd * a8[ch] - mrs * gw8[ch] + gb8[ch] + tvec[b * Hv + ch];
      o[ch] = val;
      s1 += val; s2 += val * val;
    }
    float* vo = v2 + (size_t)g * Nv * Hv + noff;   // streaming: bypass L2
    nt_store4(vo,     o[0], o[1], o[2], o[3]);
    nt_store4(vo + 4, o[4], o[5], o[6], o[7]);
  }
  partial_to_stats(s1, s2, stats2 + (size_t)g * 2);
}

// ---------------- stage 3: LN(v2) on-the-fly + 12x12 conv over P (in-place) + skip acc
// 1D grid 320 blocks: b = blockIdx%8 (keeps batch b on XCD b), chunk = blockIdx/8
__global__ __launch_bounds__(256) void k_stage3(
    float* __restrict__ v2, float* __restrict__ acc,
    const float* __restrict__ stats2,
    const float* __restrict__ tnw, const float* __restrict__ tnb,
    const float* __restrict__ cw, const float* __restrict__ cb,
    const float* __restrict__ a9, int iblk) {
  __shared__ float scw[144], scb[12], smean[12], srstd[12];
  int t = threadIdx.x;
  int b = blockIdx.x & 7;
  int chunk = blockIdx.x >> 3;
  if (t < 144) scw[t] = cw[t];
  else if (t < 156) scb[t - 144] = cb[t - 144];
  else if (t < 168) {
    int p = t - 156;
    int g = b * Pv + p;
    float mean = stats2[g * 2] * (1.f / 40000.f);
    float m2   = stats2[g * 2 + 1] * (1.f / 40000.f);
    float var  = m2 - mean * mean;
    smean[p] = mean;
    srstd[p] = (float)(1.0 / sqrt((double)var + 1e-5));
  }
  __syncthreads();
  int idx = chunk * 256 + t;
  if (idx >= Nv * 2) return;
  int n = idx >> 1, c4 = idx & 1;
  size_t noff = (size_t)n * Hv + c4 * 4;
  const float4 w4 = nt_load4(tnw + noff);   // single-use per XCD
  const float4 b4 = nt_load4(tnb + noff);
  size_t strideP = (size_t)Nv * Hv;
  size_t base = (size_t)b * Pv * strideP + noff;
  float4 in[12];
  #pragma unroll
  for (int p = 0; p < 12; ++p) {
    float4 v = nt_load4(v2 + base + p * strideP);  // dead after this read
    float mean = smean[p], rstd = srstd[p];
    in[p].x = (v.x - mean) * rstd * w4.x + b4.x;
    in[p].y = (v.y - mean) * rstd * w4.y + b4.y;
    in[p].z = (v.z - mean) * rstd * w4.z + b4.z;
    in[p].w = (v.w - mean) * rstd * w4.w + b4.w;
  }
  float ai = a9[iblk + 1];
  #pragma unroll
  for (int q = 0; q < 12; ++q) {
    float4 o = make_float4(scb[q], scb[q], scb[q], scb[q]);
    #pragma unroll
    for (int p = 0; p < 12; ++p) {
      float c = scw[q * 12 + p];
      o.x += c * in[p].x; o.y += c * in[p].y;
      o.z += c * in[p].z; o.w += c * in[p].w;
    }
    size_t off = base + q * strideP;
    *(float4*)(v2 + off) = o;        // live: next stage1 reads it -> keep in L2
    float4 av = nt_load4(acc + off); // acc: streaming RMW, keep out of L2
    nt_store4(acc + off, av.x + ai * o.x, av.y + ai * o.y,
                         av.z + ai * o.z, av.w + ai * o.w);
  }
}

// ---------------- output projection
__global__ void k_out(const float* acc, const float* ow1, const float* ob1,
                      const float* ow2, const float* ob2, float* out) {
  int t = blockIdx.x * blockDim.x + threadIdx.x;
  if (t >= Bv * Pv * Nv) return;
  float4 a0 = nt_load4(acc + (size_t)t * Hv);
  float4 a1 = nt_load4(acc + (size_t)t * Hv + 4);
  float x[8] = {a0.x, a0.y, a0.z, a0.w, a1.x, a1.y, a1.z, a1.w};
  float o = ob2[0];
  #pragma unroll
  for (int j = 0; j < 8; ++j) {
    float s = ob1[j];
    #pragma unroll
    for (int k = 0; k < 8; ++k) s += x[k] * ow1[k * 8 + j];
    o += fmaxf(s, 0.f) * ow2[j];
  }
  out[t] = o;
}

extern "C" void kernel_launch(void* const* d_in, const int* in_sizes, int n_in,
                              void* d_out, int out_size, void* d_ws, size_t ws_size,
                              hipStream_t stream) {
  const float* x      = (const float*)d_in[0];
  const float* cond   = (const float*)d_in[1];
  const float* pos    = (const float*)d_in[2];
  const int*   timei  = (const int*)  d_in[3];
  const int*   eidx   = (const int*)  d_in[4];
  const float* te_w1  = (const float*)d_in[5];
  const float* te_b1  = (const float*)d_in[6];
  const float* te_w2  = (const float*)d_in[7];
  const float* te_b2  = (const float*)d_in[8];
  const float* in_w1  = (const float*)d_in[9];
  const float* in_b1  = (const float*)d_in[10];
  const float* in_w2  = (const float*)d_in[11];
  const float* in_b2  = (const float*)d_in[12];
  const float* pos_w1 = (const float*)d_in[13];
  const float* pos_b1 = (const float*)d_in[14];
  const float* pos_w2 = (const float*)d_in[15];
  const float* pos_b2 = (const float*)d_in[16];
  const float* attn   = (const float*)d_in[17];
  const float* bt_w1  = (const float*)d_in[18];
  const float* bt_b1  = (const float*)d_in[19];
  const float* bt_w2  = (const float*)d_in[20];
  const float* bt_b2  = (const float*)d_in[21];
  const float* bc_w1  = (const float*)d_in[22];
  const float* bc_b1  = (const float*)d_in[23];
  const float* bc_w2  = (const float*)d_in[24];
  const float* bc_b2  = (const float*)d_in[25];
  const float* gn_w   = (const float*)d_in[26];
  const float* gn_b   = (const float*)d_in[27];
  const float* tn_w   = (const float*)d_in[28];
  const float* tn_b   = (const float*)d_in[29];
  const float* cv_w   = (const float*)d_in[30];
  const float* cv_b   = (const float*)d_in[31];
  const float* out_w1 = (const float*)d_in[32];
  const float* out_b1 = (const float*)d_in[33];
  const float* out_w2 = (const float*)d_in[34];
  const float* out_b2 = (const float*)d_in[35];
  float* out = (float*)d_out;

  const size_t HSZ = (size_t)Bv * Pv * Nv * Hv;  // 3,840,000
  float* ws    = (float*)d_ws;
  float* X     = ws;                 // h / v2 buffer
  float* Y     = X + HSZ;            // vt (= gnw ⊙ v1) buffer
  float* acc   = Y + HSZ;
  float* posp  = acc + HSZ;          // Nv*Hv
  float* deg   = posp + Nv * Hv;     // Nv
  float* dinv  = deg + Nv;           // Nv
  float* epack = dinv + Nv;          // 2*Ev floats
  float* t_all = epack + 2 * Ev;     // NBv*Bv*Hv = 512
  float* a9    = t_all + NBv * Bv * Hv;  // 16
  float* stats = a9 + 16;            // NBv*2*NIMG*2 = 3072
  float* Gw    = stats + NBv * 2 * NIMG * 2;  // NBv*Nv*Hv = 320000
  float* Gb    = Gw + NBv * Nv * Hv;          // 320000
  int* row_ptr = (int*)(Gb + NBv * Nv * Hv);  // Nv+8
  int* cursor  = row_ptr + Nv + 8;   // Nv+8

  k_setup<<<1, 64, 0, stream>>>(timei, attn, te_w1, te_b1, te_w2, te_b2,
                                bt_w1, bt_b1, bt_w2, bt_b2, t_all, a9);
  k_posp<<<(Nv + 255) / 256, 256, 0, stream>>>(pos, pos_w1, pos_b1, pos_w2, pos_b2, posp);
  k_zero<<<(Nv + 255) / 256, 256, 0, stream>>>(deg, cursor, stats);
  k_deg<<<(Ev + 255) / 256, 256, 0, stream>>>(eidx, deg);
  k_dinv<<<(Nv + 255) / 256, 256, 0, stream>>>(deg, dinv);
  k_scan<<<1, 1024, 0, stream>>>(deg, row_ptr);
  k_csr<<<(Ev + 255) / 256, 256, 0, stream>>>(eidx, dinv, row_ptr, cursor, (float2*)epack);
  k_gwb<<<(NBv * Nv + 255) / 256, 256, 0, stream>>>(
      row_ptr, (const float2*)epack, gn_w, gn_b, Gw, Gb);
  k_init<<<(Bv * Pv * Nv + 255) / 256, 256, 0, stream>>>(
      x, posp, in_w1, in_b1, in_w2, in_b2, a9, X, acc);

  for (int i = 0; i < NBv; ++i) {
    float* st1 = stats + (size_t)(i * 2 + 0) * NIMG * 2;
    float* st2 = stats + (size_t)(i * 2 + 1) * NIMG * 2;
    k_stage1<<<NIMG * BLKS_PER_IMG, 256, 0, stream>>>(
        X, cond,
        bc_w1 + i * 64, bc_b1 + i * 8, bc_w2 + i * 64, bc_b2 + i * 8,
        gn_w + (size_t)i * Nv * Hv,
        Y, st1);
    k_stage2<<<NIMG * BLKS_PER_IMG, 256, 0, stream>>>(
        Y, X, row_ptr, (const float2*)epack,
        Gw + (size_t)i * Nv * Hv, Gb + (size_t)i * Nv * Hv,
        st1, st2, t_all + i * Bv * Hv);
    k_stage3<<<8 * 40, 256, 0, stream>>>(
        X, acc, st2,
        tn_w + (size_t)i * Nv * Hv, tn_b + (size_t)i * Nv * Hv,
        cv_w + i * 144, cv_b + i * 12, a9, i);
  }
  k_out<<<(Bv * Pv * Nv + 255) / 256, 256, 0, stream>>>(
      acc, out_w1, out_b1, out_w2, out_b2, out);
}